// Round 8
// baseline (393.643 us; speedup 1.0000x reference)
//
#include <hip/hip_runtime.h>
#include <hip/hip_bf16.h>

typedef unsigned short u16;
typedef unsigned int u32;
typedef __bf16 bf16x8 __attribute__((ext_vector_type(8)));
typedef float f32x4 __attribute__((ext_vector_type(4)));

#define N_ 32
#define D_ 512
#define P_ 3136   // 56*56
#define K_ 64
#define NDP (D_ * P_)

// ---- workspace layout (bytes) ----
// wbf   : bf16 conv_w [64][512]            @ 0        (65536)
// a_sum : f32 [32][64]                     @ 65536    (8192)
// agg   : f32 [8][32][64][512]             @ 73728    (33554432)
// rowsq : f32 [32][64]                     @ 33628160 (8192)

__device__ __forceinline__ u16 f2bf(float f) {       // RNE float->bf16 bits
  u32 u = __float_as_uint(f);
  return (u16)((u + 0x7fffu + ((u >> 16) & 1u)) >> 16);
}
__device__ __forceinline__ u32 pack2(float a, float b) {
  return (u32)f2bf(a) | ((u32)f2bf(b) << 16);
}

// -------- KW: conv_w fp32 -> bf16 (64KB, L2-resident) --------
__global__ __launch_bounds__(256) void kw_kernel(const float* __restrict__ w,
                                                 u16* __restrict__ wbf) {
  int i = blockIdx.x * 256 + threadIdx.x;
  float4 v = ((const float4*)w)[i];
  ((uint2*)wbf)[i] = make_uint2(pack2(v.x, v.y), pack2(v.z, v.w));
}

// -------- F: fused stage -> GEMM1 -> softmax -> GEMM2, 8 waves --------
// f32 x-image, ADDITIVE swizzle (2-way banks everywhere, bijective per row):
//   byte(d,px) = d*256 + chunk*16 + (px&3)*4,
//   chunk = (px>>2 + f(d)) & 15,  f(d) = (d&7) + 2*((d>>3)&3)
// staged via global_load_lds with inverse-swizzled global source.
// a'-image (bf16): byte(k,px) = k*128 + (((px>>3)^(k&7))<<4) + (px&7)*2
// GEMM1: wave (h = w>>2, g = w&3): k-half h (32 k), px-group g (16 px);
//        2-half softmax merge via LDS pmax/psum.
// GEMM2: wave w owns d-slice [w*64, w*64+64), all 64 k -> acc2 = 64 VGPR.
__global__ __launch_bounds__(512, 2) void f_kernel(const float* __restrict__ x,
                                                   const u16* __restrict__ wbf,
                                                   float* __restrict__ agg,
                                                   float* __restrict__ a_sum) {
  __shared__ __align__(16) char xbuf[131072];    // f32 [512 d][64 px] swizzled
  __shared__ __align__(16) char a_bf[8192];      // bf16 a' [64 k][64 px] swizzled
  __shared__ float pmax[2][64];
  __shared__ float psum[2][64];

  const int t = threadIdx.x;
  const int lane = t & 63;
  const int w = t >> 6;                 // 0..7
  const int c = lane & 15;
  const int q = lane >> 4;
  const int h = w >> 2;                 // k-half
  const int g = w & 3;                  // px-group
  const int b = blockIdx.x;
  const int n = b >> 3;
  const int s = b & 7;
  const int tile0 = (s == 0) ? 0 : 7 + (s - 1) * 6;
  const int ntl = (s == 0) ? 7 : 6;
  const int rp = g * 16 + c;            // pixel in GEMM1/softmax
  const int rpc = rp >> 2;
  const int rpo = (rp & 3) * 4;
  const int c7 = c & 7;
  const int kb = h * 32;

  const bf16x8* wrow = (const bf16x8*)wbf;
  const char* xgb = (const char*)(x + (size_t)n * NDP);

  f32x4 acc2[4][4];                     // all 64 k x 64-d slice
#pragma unroll
  for (int m4 = 0; m4 < 4; ++m4)
#pragma unroll
    for (int nt = 0; nt < 4; ++nt) acc2[m4][nt] = (f32x4){0.f, 0.f, 0.f, 0.f};
  float ssum_acc[2][4];
#pragma unroll
  for (int m = 0; m < 2; ++m)
#pragma unroll
    for (int r = 0; r < 4; ++r) ssum_acc[m][r] = 0.f;

  for (int tt = 0; tt < ntl; ++tt) {
    const int p0 = (tile0 + tt) * 64;

    // ---- stage: 16 global_load_lds x 16B per wave (128KB total) ----
#pragma unroll
    for (int i = 0; i < 16; ++i) {
      const int dq = w * 64 + i * 4 + q;
      const int f = ((i * 4 + q) & 7) + 2 * ((i >> 1) & 3);   // f(dq)
      const int gch = (c - f) & 15;     // inverse swizzle on source
      const char* src = xgb + ((size_t)dq * P_ + p0) * 4 + (gch << 4);
      __builtin_amdgcn_global_load_lds(
          (const __attribute__((address_space(1))) void*)src,
          (__attribute__((address_space(3))) void*)(xbuf + w * 16384 + i * 1024),
          16, 0, 0);
    }
    __syncthreads();                    // vmcnt drained by compiler

    // ---- GEMM1: logits for k-half kb..kb+31, px-group g; sumsq rides ----
    f32x4 acc1[2];
    acc1[0] = (f32x4){0.f, 0.f, 0.f, 0.f};
    acc1[1] = (f32x4){0.f, 0.f, 0.f, 0.f};
    float sumsq = 0.f;
    bf16x8 pa[2][2];
#pragma unroll
    for (int m = 0; m < 2; ++m) {
      pa[0][m] = wrow[(kb + m * 16 + c) * 64 + q];
      pa[1][m] = wrow[(kb + m * 16 + c) * 64 + 4 + q];
    }
    float vc[8];
#pragma unroll
    for (int j = 0; j < 8; ++j) {
      const int ch = (rpc + j + 2 * q) & 15;
      vc[j] = *(const float*)(xbuf + ((q * 8 + j) << 8) + (ch << 4) + rpo);
    }
#pragma unroll
    for (int st = 0; st < 16; ++st) {
      float vn[8];
      if (st < 15) {
#pragma unroll
        for (int j = 0; j < 8; ++j) {
          const int ch = (rpc + j + 2 * q) & 15;
          vn[j] = *(const float*)(xbuf + (((st + 1) * 32 + q * 8 + j) << 8) +
                                  (ch << 4) + rpo);
        }
      }
      bf16x8 bfr;
#pragma unroll
      for (int j = 0; j < 8; ++j) {
        sumsq += vc[j] * vc[j];
        bfr[j] = (__bf16)vc[j];
      }
      bf16x8 nf[2];
      if (st < 14) {
#pragma unroll
        for (int m = 0; m < 2; ++m)
          nf[m] = wrow[(kb + m * 16 + c) * 64 + (st + 2) * 4 + q];
      }
      acc1[0] = __builtin_amdgcn_mfma_f32_16x16x32_bf16(pa[st & 1][0], bfr, acc1[0], 0, 0, 0);
      acc1[1] = __builtin_amdgcn_mfma_f32_16x16x32_bf16(pa[st & 1][1], bfr, acc1[1], 0, 0, 0);
      if (st < 14) {
        pa[st & 1][0] = nf[0];
        pa[st & 1][1] = nf[1];
      }
      if (st < 15) {
#pragma unroll
        for (int j = 0; j < 8; ++j) vc[j] = vn[j];
      }
    }

    // per-pixel inv-norm (full d via q-reduce, fp32-exact)
    sumsq += __shfl_xor(sumsq, 16);
    sumsq += __shfl_xor(sumsq, 32);
    const float inv_p = 1.f / fmaxf(sqrtf(sumsq), 1e-12f);

    // ---- softmax (local half), then 2-half merge ----
    float scv[2][4];
    float lmax = -3.0e38f;
#pragma unroll
    for (int m = 0; m < 2; ++m)
#pragma unroll
      for (int r = 0; r < 4; ++r) {
        float val = acc1[m][r] * inv_p;
        scv[m][r] = val;
        lmax = fmaxf(lmax, val);
      }
    lmax = fmaxf(lmax, __shfl_xor(lmax, 16));
    lmax = fmaxf(lmax, __shfl_xor(lmax, 32));
    float lsum = 0.f;
#pragma unroll
    for (int m = 0; m < 2; ++m)
#pragma unroll
      for (int r = 0; r < 4; ++r) {
        float e = __expf(scv[m][r] - lmax);
        scv[m][r] = e;
        lsum += e;
      }
    lsum += __shfl_xor(lsum, 16);
    lsum += __shfl_xor(lsum, 32);
    if (q == 0) {
      pmax[h][rp] = lmax;
      psum[h][rp] = lsum;
    }
    __syncthreads();
    const float m0 = pmax[0][rp], m1 = pmax[1][rp];
    const float M = fmaxf(m0, m1);
    const float S = psum[0][rp] * __expf(m0 - M) + psum[1][rp] * __expf(m1 - M);
    const float factor = __expf(lmax - M) / S;

    // ---- a' = a*inv_p -> bf16 image (direct from regs) + a_sum regs ----
#pragma unroll
    for (int m = 0; m < 2; ++m)
#pragma unroll
      for (int r = 0; r < 4; ++r) {
        const float a = scv[m][r] * factor;
        ssum_acc[m][r] += a;
        const int k = kb + m * 16 + q * 4 + r;
        const int chA = (g * 2 + (c >> 3)) ^ (k & 7);
        *(u16*)(a_bf + k * 128 + (chA << 4) + (c7 << 1)) = f2bf(a * inv_p);
      }
    __syncthreads();

    // ---- GEMM2: agg[all k, d in wave slice] += a'[k,p] * x[d,p] ----
#pragma unroll
    for (int st = 0; st < 2; ++st) {
      bf16x8 afr[4];
#pragma unroll
      for (int m4 = 0; m4 < 4; ++m4)
        afr[m4] = *(const bf16x8*)(a_bf + (m4 * 16 + c) * 128 +
                                   (((st * 4 + q) ^ c7) << 4));
      const int pc0 = st * 8 + q * 2;
#pragma unroll
      for (int nt = 0; nt < 4; ++nt) {
        const int d = w * 64 + nt * 16 + c;
        const int f = (d & 7) + 2 * ((d >> 3) & 3);
        const int ch0 = (pc0 + f) & 15;
        const int ch1 = (pc0 + 1 + f) & 15;
        f32x4 b0 = *(const f32x4*)(xbuf + (d << 8) + (ch0 << 4));
        f32x4 b1 = *(const f32x4*)(xbuf + (d << 8) + (ch1 << 4));
        bf16x8 bfr;
#pragma unroll
        for (int i4 = 0; i4 < 4; ++i4) {
          bfr[i4] = (__bf16)b0[i4];
          bfr[4 + i4] = (__bf16)b1[i4];
        }
#pragma unroll
        for (int m4 = 0; m4 < 4; ++m4)
          acc2[m4][nt] = __builtin_amdgcn_mfma_f32_16x16x32_bf16(afr[m4], bfr, acc2[m4][nt], 0, 0, 0);
      }
    }
    __syncthreads();                    // xbuf/a_bf free for next tile
  }

  // ---- epilogue: slab partial + a_sum atomics ----
  float* ob = agg + ((size_t)s * 32 + n) * (K_ * D_);
#pragma unroll
  for (int m4 = 0; m4 < 4; ++m4)
#pragma unroll
    for (int nt = 0; nt < 4; ++nt)
#pragma unroll
      for (int r = 0; r < 4; ++r)
        ob[(m4 * 16 + q * 4 + r) * D_ + w * 64 + nt * 16 + c] = acc2[m4][nt][r];
#pragma unroll
  for (int m = 0; m < 2; ++m)
#pragma unroll
    for (int r = 0; r < 4; ++r) {
      float v = ssum_acc[m][r];
      v += __shfl_xor(v, 1);
      v += __shfl_xor(v, 2);
      v += __shfl_xor(v, 4);
      v += __shfl_xor(v, 8);
      if (c == 0) atomicAdd(&a_sum[n * 64 + kb + m * 16 + q * 4 + r], v);
    }
}

// -------- K3a: vlad = sum_s agg[s] - a_sum*c ; per-row sumsq --------
__global__ __launch_bounds__(256) void k3a_kernel(const float* __restrict__ agg,
                                                  const float* __restrict__ a_sum,
                                                  const float* __restrict__ cent,
                                                  float* __restrict__ out,
                                                  float* __restrict__ rowsq) {
  const int b = blockIdx.x;             // n*16 + kg
  const int n = b >> 4, kg = b & 15;
  const int t = threadIdx.x;
  const int lane = t & 63, w = t >> 6;
  const int k = kg * 4 + w;
  const float* ab = agg + ((size_t)n * 64 + k) * 512 + lane * 8;
  float v[8];
#pragma unroll
  for (int j = 0; j < 8; ++j) v[j] = 0.f;
#pragma unroll
  for (int pp = 0; pp < 8; ++pp) {
    const float4* p4 = (const float4*)(ab + (size_t)pp * 32 * (K_ * D_));
    float4 r0 = p4[0], r1 = p4[1];
    v[0] += r0.x; v[1] += r0.y; v[2] += r0.z; v[3] += r0.w;
    v[4] += r1.x; v[5] += r1.y; v[6] += r1.z; v[7] += r1.w;
  }
  const float asum = a_sum[n * 64 + k];
  const float4* c4 = (const float4*)(cent + k * 512 + lane * 8);
  float4 c0 = c4[0], c1 = c4[1];
  v[0] -= asum * c0.x; v[1] -= asum * c0.y; v[2] -= asum * c0.z; v[3] -= asum * c0.w;
  v[4] -= asum * c1.x; v[5] -= asum * c1.y; v[6] -= asum * c1.z; v[7] -= asum * c1.w;
  float ssq = 0.f;
#pragma unroll
  for (int j = 0; j < 8; ++j) ssq += v[j] * v[j];
  ssq += __shfl_xor(ssq, 1);  ssq += __shfl_xor(ssq, 2);  ssq += __shfl_xor(ssq, 4);
  ssq += __shfl_xor(ssq, 8);  ssq += __shfl_xor(ssq, 16); ssq += __shfl_xor(ssq, 32);
  float4* o4 = (float4*)(out + (size_t)n * 32768 + k * 512 + lane * 8);
  o4[0] = make_float4(v[0], v[1], v[2], v[3]);
  o4[1] = make_float4(v[4], v[5], v[6], v[7]);
  if (lane == 0) rowsq[n * 64 + k] = ssq;
}

// -------- K3b: intra + global normalize (scale in place) --------
__global__ __launch_bounds__(256) void k3b_kernel(const float* __restrict__ rowsq,
                                                  float* __restrict__ out) {
  __shared__ float invr_s[64];
  __shared__ float gi_s;
  const int n = blockIdx.x >> 3;
  const int seg = blockIdx.x & 7;
  const int t = threadIdx.x;
  if (t < 64) {
    float r = rowsq[n * 64 + t];
    float ri = 1.f / fmaxf(sqrtf(r), 1e-12f);
    invr_s[t] = ri;
    float g = r * ri * ri;
    g += __shfl_xor(g, 1); g += __shfl_xor(g, 2); g += __shfl_xor(g, 4);
    g += __shfl_xor(g, 8); g += __shfl_xor(g, 16); g += __shfl_xor(g, 32);
    if (t == 0) gi_s = 1.f / fmaxf(sqrtf(g), 1e-12f);
  }
  __syncthreads();
  const int e0 = seg * 4096 + t * 16;
  const float sc = invr_s[e0 >> 9] * gi_s;
  float4* o4 = (float4*)(out + (size_t)n * 32768 + e0);
#pragma unroll
  for (int i = 0; i < 4; ++i) {
    float4 vv = o4[i];
    vv.x *= sc; vv.y *= sc; vv.z *= sc; vv.w *= sc;
    o4[i] = vv;
  }
}

extern "C" void kernel_launch(void* const* d_in, const int* in_sizes, int n_in,
                              void* d_out, int out_size, void* d_ws, size_t ws_size,
                              hipStream_t stream) {
  (void)in_sizes; (void)n_in; (void)out_size; (void)ws_size;
  const float* x    = (const float*)d_in[0];
  const float* cw   = (const float*)d_in[1];
  const float* cent = (const float*)d_in[2];
  float* out = (float*)d_out;
  char* ws = (char*)d_ws;
  u16*   wbf   = (u16*)(ws);
  float* a_sum = (float*)(ws + 65536);
  float* agg   = (float*)(ws + 73728);
  float* rowsq = (float*)(ws + 33628160);

  hipMemsetAsync(a_sum, 0, 64 * 32 * sizeof(float), stream);
  kw_kernel<<<32, 256, 0, stream>>>(cw, wbf);
  f_kernel<<<256, 512, 0, stream>>>(x, wbf, agg, a_sum);
  k3a_kernel<<<512, 256, 0, stream>>>(agg, a_sum, cent, out, rowsq);
  k3b_kernel<<<256, 256, 0, stream>>>(rowsq, out);
}